// Round 1
// baseline (259.506 us; speedup 1.0000x reference)
//
#include <hip/hip_runtime.h>
#include <cstdint>
#include <cstddef>

// FeatureAttention: x[4,2048,1024] fp32; Q=xWq^T+bq, K=xWk^T+bk, V=xWv^T+bv;
// out = softmax(QK^T/32) V.  bf16 MFMA pipeline.
//
// R5: 8-phase 256-row-tile GEMM (T3+T4 counted-vmcnt + T5 setprio), BN=256 or
// 128 so every GEMM is exactly 256 blocks (1/CU). Wq|Wk stacked -> one N=2048
// projection GEMM. Stage schedule per K-tile t (4 phases):
//   ph0: ds-read B frags(all)+A frags i0,i1 ; stage A-rows64..127(t+1)
//   ph1: A frags i2,i3 ; stage B-half0(t+2)
//   ph2: A frags i4,i5 ; stage B-half1(t+2) [BN=128: A-rows0..63(t+2)]
//   ph3: A frags i6,i7 ; stage A-rows0..63(t+2) [BN=128: none]; vmcnt(6/4)
//   each phase: barrier; lgkmcnt(0); setprio(1); MFMAs; setprio(0); barrier
// vmcnt(6) leaves exactly the last 3 stage-units (6 loads) in flight; all
// regions staged are dead since the preceding barrier (derivation in R5 log).
//
// Workspace (80 MB):
//   [0,16M)  Xb    [16,20) Wqkb (Wq|Wk stacked)  [20,22) Wvb
//   [32,64M) QKb   (Q|K stacked, ldc=2048)
//   [64,80M) Vt    (V transposed [1024][8192])
//   [0,32M)  Sc    (exp(scores) bf16 [4][2048][2048], reuses dead region)

typedef unsigned short ushort_t;
typedef __attribute__((ext_vector_type(8))) short short8;
typedef __attribute__((ext_vector_type(4))) float f32x4;

#define AS1 __attribute__((address_space(1)))
#define AS3 __attribute__((address_space(3)))

__device__ __forceinline__ ushort_t f2bf(float f) {
    unsigned int u = __float_as_uint(f);
    u += 0x7FFFu + ((u >> 16) & 1u);
    return (ushort_t)(u >> 16);
}
__device__ __forceinline__ float bf2f(ushort_t b) {
    return __uint_as_float(((unsigned)b) << 16);
}

// async global->LDS, 16B/lane; lds dest = wave-uniform base + lane*16
__device__ __forceinline__ void async_ld16(const void* g, unsigned lds_off) {
    __builtin_amdgcn_global_load_lds((const AS1 void*)(uintptr_t)g,
                                     (AS3 void*)(uintptr_t)lds_off,
                                     16, 0, 0);
}

template <int N>
__device__ __forceinline__ void wait_vmcnt() {
    if constexpr (N == 0)      asm volatile("s_waitcnt vmcnt(0)" ::: "memory");
    else if constexpr (N == 4) asm volatile("s_waitcnt vmcnt(4)" ::: "memory");
    else                       asm volatile("s_waitcnt vmcnt(6)" ::: "memory");
}

// ---------------------------------------------------------------------------
// 8-phase BT-GEMM. BM=256, BK=64, 512 threads (8 waves as 2M x 4N).
//   C[m*ldc+n] = epi( scale * sum_k A[m*lda+k] * B[n*ldb+k] )
// EPI: 1 +bias(n): n<1024 ? bias0[n] : bias1[n-1024]
//      2 +bias0[m] | 3 exp(v) | 4 v / rowsum(A-tile row m) (in-kernel rowsum)
// Bank swizzle: 16B chunk c of row r stored at pos (c+r)&7 (applied on the
// staging *source* chunk; global_load_lds lane->LDS map is fixed).
// ---------------------------------------------------------------------------
template <typename OT, int EPI, int BN>
__global__ __launch_bounds__(512, 2) void gemm8(
    const ushort_t* __restrict__ A, const ushort_t* __restrict__ B,
    const float* __restrict__ bias0, const float* __restrict__ bias1,
    OT* __restrict__ C, int K, int lda, int ldb, int ldc, float scale,
    long long aOffZ, long long bOffZ, long long cOffZ)
{
    constexpr int NJ   = BN / 64;              // 4 (BN=256) or 2 (BN=128)
    constexpr int NBH  = (BN == 256) ? 2 : 1;  // B halves
    constexpr int VPRO = (BN == 256) ? 6 : 4;  // steady-state vmcnt

    __shared__ __align__(16) ushort_t As[2][2][128 * 64];
    __shared__ __align__(16) ushort_t Bs[2][NBH][128 * 64];
    __shared__ float rs[256];                  // EPI==4 only

    const int tid  = threadIdx.x;
    const int wave = tid >> 6;
    const int lane = tid & 63;

    A += (size_t)blockIdx.z * aOffZ;
    B += (size_t)blockIdx.z * bOffZ;

    const int m0 = blockIdx.y * 256;
    const int n0 = blockIdx.x * BN;
    const int g  = wave >> 2;                  // A half (wm group)
    const int wm = g * 128;
    const int wn = (wave & 3) * (BN / 4);

    // staging map: 64 rows/call, 8 rows/wave; swizzled source chunk
    const int srow = wave * 8 + (lane >> 3);
    const int cd   = ((lane & 7) - srow) & 7;
    const unsigned lw = (unsigned)(wave << 10);

    const ushort_t* Ast = A + (size_t)(m0 + srow) * lda + cd * 8;
    const ushort_t* Bst = B + (size_t)(n0 + srow) * ldb + cd * 8;

    unsigned aB[2][2], bB[2][NBH];
#pragma unroll
    for (int b2 = 0; b2 < 2; ++b2) {
        aB[b2][0] = (unsigned)(uintptr_t)&As[b2][0][0];
        aB[b2][1] = (unsigned)(uintptr_t)&As[b2][1][0];
#pragma unroll
        for (int h = 0; h < NBH; ++h)
            bB[b2][h] = (unsigned)(uintptr_t)&Bs[b2][h][0];
    }

    // stage A rows rsel*64..rsel*64+63 of BOTH halves of K-tile t (2 loads)
    auto stA = [&](int t, int rsel) {
        const int buf = t & 1;
        const int k0  = t << 6;
        async_ld16(Ast + (size_t)(rsel * 64) * lda + k0,
                   aB[buf][0] + (unsigned)(rsel * 8192) + lw);
        async_ld16(Ast + (size_t)(rsel * 64 + 128) * lda + k0,
                   aB[buf][1] + (unsigned)(rsel * 8192) + lw);
    };
    // stage B half h (128 rows) of K-tile t (2 loads)
    auto stB = [&](int t, int h) {
        const int buf = t & 1;
        const int k0  = t << 6;
        async_ld16(Bst + (size_t)(h * 128) * ldb + k0, bB[buf][h] + lw);
        async_ld16(Bst + (size_t)(h * 128 + 64) * ldb + k0,
                   bB[buf][h] + 8192 + lw);
    };

    // fragment map
    const int frow = lane & 15;
    const int fg   = lane >> 4;
    const int hB   = (BN == 256) ? (wn >> 7) : 0;

    const int NT = K >> 6;

    f32x4 acc[8][NJ] = {};
    float rsacc[8] = {};
    short8 bfr[NJ][2];

    // prologue: steady-state issue order B0(0)[,B1(0)],Aa(0),Ab(0),B0(1)[,B1(1)],Aa(1)
    stB(0, 0);
    if (BN == 256) stB(0, 1);
    stA(0, 0); stA(0, 1);
    stB(1, 0);
    if (BN == 256) stB(1, 1);
    stA(1, 0);
    wait_vmcnt<VPRO>();            // forces all of K-tile 0 landed
    __builtin_amdgcn_s_barrier();

    for (int t = 0; t < NT; ++t) {
        const int buf = t & 1;
        const ushort_t* Aw = &As[buf][g][0];
        const ushort_t* Bw = &Bs[buf][hB][0];
#pragma unroll
        for (int ph = 0; ph < 4; ++ph) {
            short8 af[2][2];
#pragma unroll
            for (int di = 0; di < 2; ++di) {
                const int r = (ph * 2 + di) * 16 + frow;
#pragma unroll
                for (int kk = 0; kk < 2; ++kk)
                    af[di][kk] = *(const short8*)
                        &Aw[r * 64 + (((kk << 2) + fg + r) & 7) * 8];
            }
            if (ph == 0) {
#pragma unroll
                for (int j = 0; j < NJ; ++j) {
                    const int rb = (wn & 127) + j * 16 + frow;
#pragma unroll
                    for (int kk = 0; kk < 2; ++kk)
                        bfr[j][kk] = *(const short8*)
                            &Bw[rb * 64 + (((kk << 2) + fg + rb) & 7) * 8];
                }
                if (t + 1 < NT) stA(t + 1, 1);       // A rows 64-127 (t+1)
            }
            if (ph == 1 && t + 2 < NT) stB(t + 2, 0);
            if (ph == 2 && t + 2 < NT) {
                if (BN == 256) stB(t + 2, 1);
                else           stA(t + 2, 0);
            }
            if (ph == 3) {
                if (BN == 256 && t + 2 < NT) stA(t + 2, 0);
                if (t + 2 < NT)      wait_vmcnt<VPRO>();
                else if (t + 1 < NT) wait_vmcnt<0>();
            }
            __builtin_amdgcn_s_barrier();
            asm volatile("s_waitcnt lgkmcnt(0)" ::: "memory");
            __builtin_amdgcn_s_setprio(1);
#pragma unroll
            for (int di = 0; di < 2; ++di)
#pragma unroll
                for (int j = 0; j < NJ; ++j)
#pragma unroll
                    for (int kk = 0; kk < 2; ++kk)
                        acc[ph * 2 + di][j] =
                            __builtin_amdgcn_mfma_f32_16x16x32_bf16(
                                af[di][kk], bfr[j][kk],
                                acc[ph * 2 + di][j], 0, 0, 0);
            __builtin_amdgcn_s_setprio(0);
            if (EPI == 4 && wn == 0) {               // rowsum of streamed A
#pragma unroll
                for (int di = 0; di < 2; ++di)
#pragma unroll
                    for (int kk = 0; kk < 2; ++kk)
#pragma unroll
                        for (int e = 0; e < 8; ++e)
                            rsacc[ph * 2 + di] += bf2f((ushort_t)af[di][kk][e]);
            }
            __builtin_amdgcn_s_barrier();
        }
    }

    if (EPI == 4) {
        if (wn == 0) {
#pragma unroll
            for (int i = 0; i < 8; ++i) {
                float s = rsacc[i];
                s += __shfl_xor(s, 16, 64);
                s += __shfl_xor(s, 32, 64);
                rs[wm + i * 16 + frow] = s;          // 4 lanes, same value/addr
            }
        }
        __syncthreads();
    }

    // C/D layout: lane l reg r -> row (l>>4)*4+r, col l&15
    C += (size_t)blockIdx.z * cOffZ;
    const int r0 = fg << 2;
    const int c0 = lane & 15;
#pragma unroll
    for (int i = 0; i < 8; ++i) {
        float bm[4];
        if (EPI == 2) {
#pragma unroll
            for (int r = 0; r < 4; ++r)
                bm[r] = bias0[m0 + wm + i * 16 + r0 + r];
        }
        if (EPI == 4) {
#pragma unroll
            for (int r = 0; r < 4; ++r)
                bm[r] = 1.0f / rs[wm + i * 16 + r0 + r];
        }
#pragma unroll
        for (int j = 0; j < NJ; ++j) {
            const int n = n0 + wn + j * 16 + c0;
            float bn = 0.f;
            if (EPI == 1) bn = (n < 1024) ? bias0[n] : bias1[n - 1024];
#pragma unroll
            for (int r = 0; r < 4; ++r) {
                const int m = m0 + wm + i * 16 + r0 + r;
                float v = acc[i][j][r] * scale;
                if (EPI == 1) v += bn;
                if (EPI == 2) v += bm[r];
                if (EPI == 3) v = __expf(v);
                if (EPI == 4) v *= bm[r];
                if constexpr (sizeof(OT) == 2)
                    C[(size_t)m * ldc + n] = f2bf(v);
                else
                    C[(size_t)m * ldc + n] = v;
            }
        }
    }
}

// one-shot fp32->bf16 cast of x, Wq, Wk, Wv (block-range dispatch)
__global__ __launch_bounds__(256) void cvt_all(
    const float* __restrict__ x,  const float* __restrict__ wq,
    const float* __restrict__ wk, const float* __restrict__ wv,
    ushort_t* __restrict__ xb,  ushort_t* __restrict__ wqb,
    ushort_t* __restrict__ wkb, ushort_t* __restrict__ wvb)
{
    const int b = blockIdx.x;
    const float* src; ushort_t* dst; size_t base;
    if (b < 4096)      { src = x;  dst = xb;  base = (size_t)b * 2048; }
    else if (b < 4608) { src = wq; dst = wqb; base = (size_t)(b - 4096) * 2048; }
    else if (b < 5120) { src = wk; dst = wkb; base = (size_t)(b - 4608) * 2048; }
    else               { src = wv; dst = wvb; base = (size_t)(b - 5120) * 2048; }
    const size_t i = base + threadIdx.x * 8;
    const f32x4 a = *(const f32x4*)(src + i);
    const f32x4 c = *(const f32x4*)(src + i + 4);
    short8 o;
    o[0] = (short)f2bf(a[0]); o[1] = (short)f2bf(a[1]);
    o[2] = (short)f2bf(a[2]); o[3] = (short)f2bf(a[3]);
    o[4] = (short)f2bf(c[0]); o[5] = (short)f2bf(c[1]);
    o[6] = (short)f2bf(c[2]); o[7] = (short)f2bf(c[3]);
    *(short8*)(dst + i) = o;
}

extern "C" void kernel_launch(void* const* d_in, const int* in_sizes, int n_in,
                              void* d_out, int out_size, void* d_ws, size_t ws_size,
                              hipStream_t stream)
{
    const float* x  = (const float*)d_in[0];
    const float* Wq = (const float*)d_in[1];
    const float* bq = (const float*)d_in[2];
    const float* Wk = (const float*)d_in[3];
    const float* bk = (const float*)d_in[4];
    const float* Wv = (const float*)d_in[5];
    const float* bv = (const float*)d_in[6];
    float* out = (float*)d_out;

    char* ws = (char*)d_ws;
    const size_t MB = 1ull << 20;
    ushort_t* Xb   = (ushort_t*)(ws);
    ushort_t* Wqkb = (ushort_t*)(ws + 16 * MB);   // Wq rows 0-1023, Wk rows 1024-2047
    ushort_t* Wkb  = (ushort_t*)(ws + 18 * MB);
    ushort_t* Wvb  = (ushort_t*)(ws + 20 * MB);
    ushort_t* QKb  = (ushort_t*)(ws + 32 * MB);   // [8192][2048]: Q cols 0-1023, K 1024-2047
    ushort_t* Vt   = (ushort_t*)(ws + 64 * MB);   // [1024][8192]
    ushort_t* Sc   = (ushort_t*)(ws);             // reuses dead Xb/W region

    // 1) all casts in one launch
    cvt_all<<<dim3(5632), dim3(256), 0, stream>>>(
        x, Wq, Wk, Wv, Xb, Wqkb, Wkb, Wvb);

    // 2) fused Q|K projection: one GEMM, B = stacked [Wq;Wk] (2048x1024)
    gemm8<ushort_t, 1, 256><<<dim3(8, 32, 1), dim3(512), 0, stream>>>(
        Xb, Wqkb, bq, bk, QKb, 1024, 1024, 1024, 2048, 1.0f, 0, 0, 0);

    // 3) Vt = Wv X^T + bv(row)  [1024,8192]
    gemm8<ushort_t, 2, 128><<<dim3(64, 4, 1), dim3(512), 0, stream>>>(
        Wvb, Xb, bv, nullptr, Vt, 1024, 1024, 1024, 8192, 1.0f, 0, 0, 0);

    // 4) Sc = exp(Q K^T / 32)  per batch (max-free softmax numerator)
    gemm8<ushort_t, 3, 256><<<dim3(8, 8, 4), dim3(512), 0, stream>>>(
        QKb, QKb + 1024, nullptr, nullptr, Sc, 1024, 2048, 2048, 2048,
        0.03125f, 2048ll * 2048, 2048ll * 2048, 2048ll * 2048);

    // 5) out = (Sc Vt^T) / rowsum(Sc row), rowsum fused in-kernel
    gemm8<float, 4, 128><<<dim3(8, 8, 4), dim3(512), 0, stream>>>(
        Sc, Vt, nullptr, nullptr, out, 2048, 2048, 8192, 1024, 1.0f,
        2048ll * 2048, 2048ll, 2048ll * 1024);
}

// Round 2
// 257.095 us; speedup vs baseline: 1.0094x; 1.0094x over previous
//
#include <hip/hip_runtime.h>
#include <cstdint>
#include <cstddef>

// FeatureAttention: x[4,2048,1024] fp32; Q=xWq^T+bq, K=xWk^T+bk, V=xWv^T+bv;
// out = softmax(QK^T/32) V.  bf16 MFMA pipeline.
//
// R6: R5's 8-phase 256-row GEMM + (a) T1 XCD-aware 2D-chunked block remap
// (grids are 8*32 blocks; XCD = linear%8; each XCD gets a CXxCYxCZ compact
// chunk so panel k-slabs are shared in its private L2 -> kills the 8x
// A-panel re-fetch seen at 139 MB FETCH_SIZE), and (b) BN=128 path merged
// to 2 phases x 16 MFMA per K-tile (halves barrier overhead for Vt/PV).
//
// Stage schedule per K-tile t (BN=256, 4 phases):
//   ph0: ds-read B frags + A rg0,1 ; stage A-rows64..127(t+1)
//   ph1: A rg2,3 ; stage B-half0(t+2)
//   ph2: A rg4,5 ; stage B-half1(t+2)
//   ph3: A rg6,7 ; stage A-rows0..63(t+2); vmcnt(6)
// BN=128, 2 phases:
//   ph0: B frags + A rg0..3 ; stage A-rows64..127(t+1)
//   ph1: A rg4..7 ; stage B(t+2), A-rows0..63(t+2); vmcnt(4)
// each phase: barrier; lgkmcnt(0); setprio(1); MFMAs; setprio(0); barrier
//
// Workspace (80 MB):
//   [0,16M)  Xb    [16,20) Wqkb (Wq|Wk stacked)  [20,22) Wvb
//   [32,64M) QKb   (Q|K stacked, ldc=2048)
//   [64,80M) Vt    (V transposed [1024][8192])
//   [0,32M)  Sc    (exp(scores) bf16 [4][2048][2048], reuses dead region)

typedef unsigned short ushort_t;
typedef __attribute__((ext_vector_type(8))) short short8;
typedef __attribute__((ext_vector_type(4))) float f32x4;

#define AS1 __attribute__((address_space(1)))
#define AS3 __attribute__((address_space(3)))

__device__ __forceinline__ ushort_t f2bf(float f) {
    unsigned int u = __float_as_uint(f);
    u += 0x7FFFu + ((u >> 16) & 1u);
    return (ushort_t)(u >> 16);
}
__device__ __forceinline__ float bf2f(ushort_t b) {
    return __uint_as_float(((unsigned)b) << 16);
}

// async global->LDS, 16B/lane; lds dest = wave-uniform base + lane*16
__device__ __forceinline__ void async_ld16(const void* g, unsigned lds_off) {
    __builtin_amdgcn_global_load_lds((const AS1 void*)(uintptr_t)g,
                                     (AS3 void*)(uintptr_t)lds_off,
                                     16, 0, 0);
}

template <int N>
__device__ __forceinline__ void wait_vmcnt() {
    if constexpr (N == 0)      asm volatile("s_waitcnt vmcnt(0)" ::: "memory");
    else if constexpr (N == 4) asm volatile("s_waitcnt vmcnt(4)" ::: "memory");
    else                       asm volatile("s_waitcnt vmcnt(6)" ::: "memory");
}

// ---------------------------------------------------------------------------
// 8-phase BT-GEMM. BM=256, BK=64, 512 threads (8 waves as 2M x 4N).
//   C[m*ldc+n] = epi( scale * sum_k A[m*lda+k] * B[n*ldb+k] )
// EPI: 1 +bias(n): n<1024 ? bias0[n] : bias1[n-1024]
//      2 +bias0[m] | 3 exp(v) | 4 v / rowsum(A-tile row m) (in-kernel rowsum)
// Bank swizzle: 16B chunk c of row r stored at pos (c+r)&7 (applied on the
// staging *source* chunk; global_load_lds lane->LDS map is fixed).
// CX,CY: XCD chunk dims (CX*CY*CZ = 32 blocks per XCD; grid must be 256).
// ---------------------------------------------------------------------------
template <typename OT, int EPI, int BN, int CX, int CY>
__global__ __launch_bounds__(512, 2) void gemm8(
    const ushort_t* __restrict__ A, const ushort_t* __restrict__ B,
    const float* __restrict__ bias0, const float* __restrict__ bias1,
    OT* __restrict__ C, int K, int lda, int ldb, int ldc, float scale,
    long long aOffZ, long long bOffZ, long long cOffZ)
{
    constexpr int NJ   = BN / 64;              // 4 (BN=256) or 2 (BN=128)
    constexpr int NBH  = (BN == 256) ? 2 : 1;  // B halves
    constexpr int VPRO = (BN == 256) ? 6 : 4;  // steady-state vmcnt
    constexpr int NPH  = (BN == 256) ? 4 : 2;  // phases per K-tile
    constexpr int DPP  = 8 / NPH;              // A row-groups per phase
    constexpr int CZ   = 32 / (CX * CY);

    __shared__ __align__(16) ushort_t As[2][2][128 * 64];
    __shared__ __align__(16) ushort_t Bs[2][NBH][128 * 64];
    __shared__ float rs[256];                  // EPI==4 only

    const int tid  = threadIdx.x;
    const int wave = tid >> 6;
    const int lane = tid & 63;

    // ---- T1: XCD-aware 2D-chunked remap (nwg==256; XCD = linear%8) ----
    const int GX  = gridDim.x, GY = gridDim.y;
    const int bid = blockIdx.x + GX * (blockIdx.y + GY * blockIdx.z);
    const int xcd = bid & 7;
    const int jj  = bid >> 3;                  // 0..31 within XCD
    const int NCX = GX / CX, NCY = GY / CY;
    const int cx  = xcd % NCX, ctt = xcd / NCX;
    const int cy  = ctt % NCY, cz  = ctt / NCY;
    const int bx  = cx * CX + (jj % CX);
    const int by  = cy * CY + ((jj / CX) % CY);
    const int bz  = cz * CZ + jj / (CX * CY);

    A += (size_t)bz * aOffZ;
    B += (size_t)bz * bOffZ;

    const int m0 = by * 256;
    const int n0 = bx * BN;
    const int g  = wave >> 2;                  // A half (wm group)
    const int wm = g * 128;
    const int wn = (wave & 3) * (BN / 4);

    // staging map: 64 rows/call, 8 rows/wave; swizzled source chunk
    const int srow = wave * 8 + (lane >> 3);
    const int cd   = ((lane & 7) - srow) & 7;
    const unsigned lw = (unsigned)(wave << 10);

    const ushort_t* Ast = A + (size_t)(m0 + srow) * lda + cd * 8;
    const ushort_t* Bst = B + (size_t)(n0 + srow) * ldb + cd * 8;

    unsigned aB[2][2], bB[2][NBH];
#pragma unroll
    for (int b2 = 0; b2 < 2; ++b2) {
        aB[b2][0] = (unsigned)(uintptr_t)&As[b2][0][0];
        aB[b2][1] = (unsigned)(uintptr_t)&As[b2][1][0];
#pragma unroll
        for (int h = 0; h < NBH; ++h)
            bB[b2][h] = (unsigned)(uintptr_t)&Bs[b2][h][0];
    }

    // stage A rows rsel*64..rsel*64+63 of BOTH halves of K-tile t (2 loads)
    auto stA = [&](int t, int rsel) {
        const int buf = t & 1;
        const int k0  = t << 6;
        async_ld16(Ast + (size_t)(rsel * 64) * lda + k0,
                   aB[buf][0] + (unsigned)(rsel * 8192) + lw);
        async_ld16(Ast + (size_t)(rsel * 64 + 128) * lda + k0,
                   aB[buf][1] + (unsigned)(rsel * 8192) + lw);
    };
    // stage B half h (128 rows) of K-tile t (2 loads)
    auto stB = [&](int t, int h) {
        const int buf = t & 1;
        const int k0  = t << 6;
        async_ld16(Bst + (size_t)(h * 128) * ldb + k0, bB[buf][h] + lw);
        async_ld16(Bst + (size_t)(h * 128 + 64) * ldb + k0,
                   bB[buf][h] + 8192 + lw);
    };

    // fragment map
    const int frow = lane & 15;
    const int fg   = lane >> 4;
    const int hB   = (BN == 256) ? (wn >> 7) : 0;

    const int NT = K >> 6;

    f32x4 acc[8][NJ] = {};
    float rsacc[8] = {};
    short8 bfr[NJ][2];

    // prologue: steady-state issue order B(0),A(0,s0),A(0,s1),B(1),A(1,s0)
    stB(0, 0);
    if (BN == 256) stB(0, 1);
    stA(0, 0); stA(0, 1);
    stB(1, 0);
    if (BN == 256) stB(1, 1);
    stA(1, 0);
    wait_vmcnt<VPRO>();            // forces all of K-tile 0 landed
    __builtin_amdgcn_s_barrier();

    for (int t = 0; t < NT; ++t) {
        const int buf = t & 1;
        const ushort_t* Aw = &As[buf][g][0];
        const ushort_t* Bw = &Bs[buf][hB][0];
#pragma unroll
        for (int ph = 0; ph < NPH; ++ph) {
            short8 af[DPP][2];
#pragma unroll
            for (int di = 0; di < DPP; ++di) {
                const int r = (ph * DPP + di) * 16 + frow;
#pragma unroll
                for (int kk = 0; kk < 2; ++kk)
                    af[di][kk] = *(const short8*)
                        &Aw[r * 64 + (((kk << 2) + fg + r) & 7) * 8];
            }
            if (ph == 0) {
#pragma unroll
                for (int j = 0; j < NJ; ++j) {
                    const int rb = (wn & 127) + j * 16 + frow;
#pragma unroll
                    for (int kk = 0; kk < 2; ++kk)
                        bfr[j][kk] = *(const short8*)
                            &Bw[rb * 64 + (((kk << 2) + fg + rb) & 7) * 8];
                }
                if (t + 1 < NT) stA(t + 1, 1);       // A rows 64-127 (t+1)
            }
            if (NPH == 4) {
                if (ph == 1 && t + 2 < NT) stB(t + 2, 0);
                if (ph == 2 && t + 2 < NT) stB(t + 2, 1);
                if (ph == 3) {
                    if (t + 2 < NT)      { stA(t + 2, 0); wait_vmcnt<VPRO>(); }
                    else if (t + 1 < NT) wait_vmcnt<0>();
                }
            } else {
                if (ph == 1) {
                    if (t + 2 < NT) { stB(t + 2, 0); stA(t + 2, 0);
                                      wait_vmcnt<VPRO>(); }
                    else if (t + 1 < NT) wait_vmcnt<0>();
                }
            }
            __builtin_amdgcn_s_barrier();
            asm volatile("s_waitcnt lgkmcnt(0)" ::: "memory");
            __builtin_amdgcn_s_setprio(1);
#pragma unroll
            for (int di = 0; di < DPP; ++di)
#pragma unroll
                for (int j = 0; j < NJ; ++j)
#pragma unroll
                    for (int kk = 0; kk < 2; ++kk)
                        acc[ph * DPP + di][j] =
                            __builtin_amdgcn_mfma_f32_16x16x32_bf16(
                                af[di][kk], bfr[j][kk],
                                acc[ph * DPP + di][j], 0, 0, 0);
            __builtin_amdgcn_s_setprio(0);
            if (EPI == 4 && wn == 0) {               // rowsum of streamed A
#pragma unroll
                for (int di = 0; di < DPP; ++di)
#pragma unroll
                    for (int kk = 0; kk < 2; ++kk)
#pragma unroll
                        for (int e = 0; e < 8; ++e)
                            rsacc[ph * DPP + di] +=
                                bf2f((ushort_t)af[di][kk][e]);
            }
            __builtin_amdgcn_s_barrier();
        }
    }

    if (EPI == 4) {
        if (wn == 0) {
#pragma unroll
            for (int i = 0; i < 8; ++i) {
                float s = rsacc[i];
                s += __shfl_xor(s, 16, 64);
                s += __shfl_xor(s, 32, 64);
                rs[wm + i * 16 + frow] = s;          // 4 lanes, same value/addr
            }
        }
        __syncthreads();
    }

    // C/D layout: lane l reg r -> row (l>>4)*4+r, col l&15
    C += (size_t)bz * cOffZ;
    const int r0 = fg << 2;
    const int c0 = lane & 15;
#pragma unroll
    for (int i = 0; i < 8; ++i) {
        float bm[4];
        if (EPI == 2) {
#pragma unroll
            for (int r = 0; r < 4; ++r)
                bm[r] = bias0[m0 + wm + i * 16 + r0 + r];
        }
        if (EPI == 4) {
#pragma unroll
            for (int r = 0; r < 4; ++r)
                bm[r] = 1.0f / rs[wm + i * 16 + r0 + r];
        }
#pragma unroll
        for (int j = 0; j < NJ; ++j) {
            const int n = n0 + wn + j * 16 + c0;
            float bn = 0.f;
            if (EPI == 1) bn = (n < 1024) ? bias0[n] : bias1[n - 1024];
#pragma unroll
            for (int r = 0; r < 4; ++r) {
                const int m = m0 + wm + i * 16 + r0 + r;
                float v = acc[i][j][r] * scale;
                if (EPI == 1) v += bn;
                if (EPI == 2) v += bm[r];
                if (EPI == 3) v = __expf(v);
                if (EPI == 4) v *= bm[r];
                if constexpr (sizeof(OT) == 2)
                    C[(size_t)m * ldc + n] = f2bf(v);
                else
                    C[(size_t)m * ldc + n] = v;
            }
        }
    }
}

// one-shot fp32->bf16 cast of x, Wq, Wk, Wv (block-range dispatch)
__global__ __launch_bounds__(256) void cvt_all(
    const float* __restrict__ x,  const float* __restrict__ wq,
    const float* __restrict__ wk, const float* __restrict__ wv,
    ushort_t* __restrict__ xb,  ushort_t* __restrict__ wqb,
    ushort_t* __restrict__ wkb, ushort_t* __restrict__ wvb)
{
    const int b = blockIdx.x;
    const float* src; ushort_t* dst; size_t base;
    if (b < 4096)      { src = x;  dst = xb;  base = (size_t)b * 2048; }
    else if (b < 4608) { src = wq; dst = wqb; base = (size_t)(b - 4096) * 2048; }
    else if (b < 5120) { src = wk; dst = wkb; base = (size_t)(b - 4608) * 2048; }
    else               { src = wv; dst = wvb; base = (size_t)(b - 5120) * 2048; }
    const size_t i = base + threadIdx.x * 8;
    const f32x4 a = *(const f32x4*)(src + i);
    const f32x4 c = *(const f32x4*)(src + i + 4);
    short8 o;
    o[0] = (short)f2bf(a[0]); o[1] = (short)f2bf(a[1]);
    o[2] = (short)f2bf(a[2]); o[3] = (short)f2bf(a[3]);
    o[4] = (short)f2bf(c[0]); o[5] = (short)f2bf(c[1]);
    o[6] = (short)f2bf(c[2]); o[7] = (short)f2bf(c[3]);
    *(short8*)(dst + i) = o;
}

extern "C" void kernel_launch(void* const* d_in, const int* in_sizes, int n_in,
                              void* d_out, int out_size, void* d_ws, size_t ws_size,
                              hipStream_t stream)
{
    const float* x  = (const float*)d_in[0];
    const float* Wq = (const float*)d_in[1];
    const float* bq = (const float*)d_in[2];
    const float* Wk = (const float*)d_in[3];
    const float* bk = (const float*)d_in[4];
    const float* Wv = (const float*)d_in[5];
    const float* bv = (const float*)d_in[6];
    float* out = (float*)d_out;

    char* ws = (char*)d_ws;
    const size_t MB = 1ull << 20;
    ushort_t* Xb   = (ushort_t*)(ws);
    ushort_t* Wqkb = (ushort_t*)(ws + 16 * MB);   // Wq rows 0-1023, Wk rows 1024-2047
    ushort_t* Wvb  = (ushort_t*)(ws + 20 * MB);
    ushort_t* QKb  = (ushort_t*)(ws + 32 * MB);   // [8192][2048]: Q cols 0-1023, K 1024-2047
    ushort_t* Vt   = (ushort_t*)(ws + 64 * MB);   // [1024][8192]
    ushort_t* Sc   = (ushort_t*)(ws);             // reuses dead Xb/W region

    // 1) all casts in one launch
    cvt_all<<<dim3(5632), dim3(256), 0, stream>>>(
        x, Wq, Wk, Wv, Xb, Wqkb, (ushort_t*)(ws + 18 * MB), Wvb);

    // 2) fused Q|K projection: one GEMM, B = stacked [Wq;Wk] (2048x1024)
    //    chunk 4x x 8y: XCD = half-N x quarter-M; fetch ~6 MB/XCD
    gemm8<ushort_t, 1, 256, 4, 8><<<dim3(8, 32, 1), dim3(512), 0, stream>>>(
        Xb, Wqkb, bq, bk, QKb, 1024, 1024, 1024, 2048, 1.0f, 0, 0, 0);

    // 3) Vt = Wv X^T + bv(row)  [1024,8192]; chunk 8x x 4y (all M)
    gemm8<ushort_t, 2, 128, 8, 4><<<dim3(64, 4, 1), dim3(512), 0, stream>>>(
        Wvb, Xb, bv, nullptr, Vt, 1024, 1024, 1024, 8192, 1.0f, 0, 0, 0);

    // 4) Sc = exp(Q K^T / 32) per batch; chunk 4x x 8y (half batch per XCD)
    gemm8<ushort_t, 3, 256, 4, 8><<<dim3(8, 8, 4), dim3(512), 0, stream>>>(
        QKb, QKb + 1024, nullptr, nullptr, Sc, 1024, 2048, 2048, 2048,
        0.03125f, 2048ll * 2048, 2048ll * 2048, 2048ll * 2048);

    // 5) out = (Sc Vt^T) / rowsum(Sc row); chunk 8x x 4y x 1z
    //    (8 x-blocks share each 1 MB Sc panel within one XCD)
    gemm8<float, 4, 128, 8, 4><<<dim3(8, 8, 4), dim3(512), 0, stream>>>(
        Sc, Vt, nullptr, nullptr, out, 2048, 2048, 8192, 1024, 1.0f,
        2048ll * 2048, 2048ll, 2048ll * 1024);
}

// Round 5
// 250.425 us; speedup vs baseline: 1.0363x; 1.0266x over previous
//
#include <hip/hip_runtime.h>
#include <cstdint>
#include <cstddef>

// FeatureAttention: x[4,2048,1024] fp32; Q=xWq^T+bq, K=xWk^T+bk, V=xWv^T+bv;
// out = softmax(QK^T/32) V.  bf16 MFMA pipeline.
//
// R9 = third submission of the R7 experiment (R7/R8 died to container infra,
// no kernel verdict; remap bijectivity + address bounds re-audited clean).
// R7 = R4 (best measured: 128x128 2-barrier tiles, 2-4 blocks/CU TLP)
//      + T1 bijective XCD-chunked block remap (proven in R6: FETCH 139->33MB).
// R5/R6's 8-phase 1-block/CU structure regressed (lockstep barriers with no
// cross-block overlap at K=1024..2048); reverted.
//
// Remap: XCD = linear%8 owns a compact CXxCYxCZ sub-rectangle of the grid so
// co-resident blocks share A/B panel k-slabs in the XCD-private L2.
//
// Workspace (80 MB):
//   [0,16M)  Xb    [16,18) Wqb  [18,20) Wkb  [20,22) Wvb   (dead after proj)
//   [32,48M) Qb    [48,64M) Kb   (dead after scores)
//   [64,80M) Vt    (V transposed [1024][8192])
//   [0,32M)  Sc    (exp(scores) bf16 [4][2048][2048], reuses dead region)

typedef unsigned short ushort_t;
typedef __attribute__((ext_vector_type(8))) short short8;
typedef __attribute__((ext_vector_type(4))) float f32x4;

#define AS1 __attribute__((address_space(1)))
#define AS3 __attribute__((address_space(3)))

__device__ __forceinline__ ushort_t f2bf(float f) {
    unsigned int u = __float_as_uint(f);
    u += 0x7FFFu + ((u >> 16) & 1u);
    return (ushort_t)(u >> 16);
}
__device__ __forceinline__ float bf2f(ushort_t b) {
    return __uint_as_float(((unsigned)b) << 16);
}

// async global->LDS, 16B/lane; lds dest = wave-uniform base + lane*16
__device__ __forceinline__ void async_ld16(const void* g, unsigned lds_off) {
    __builtin_amdgcn_global_load_lds((const AS1 void*)(uintptr_t)g,
                                     (AS3 void*)(uintptr_t)lds_off,
                                     16, 0, 0);
}

// ---------------------------------------------------------------------------
// BT-GEMM, 128x128 tile, NB outputs sharing the A tile.
//   C_o[m*ldc+n] = epi( scale * sum_k A[m*lda+k] * B_o[n*ldb+k] )
// EPI: 0 none | 1 +bias_o[n] | 2 +bias0[m] | 3 exp(v)
//      | 4 v / rowsum(A-tile row m)   (rowsum computed in-kernel)
// Bank swizzle: 16B chunk c of row r stored at position (c+r)&(P-1), P=BK/8,
// applied on the staging *source* col (global_load_lds lane->LDS map fixed).
// CX,CY: XCD chunk dims; requires GX%CX==0, GY%CY==0 and
//        (GX/CX)*(GY/CY)*(GZ/CZ) == 8 with CZ = (nwg/8)/(CX*CY) integer.
// ---------------------------------------------------------------------------
template <typename OT, int EPI, int NB, int BK, int CX, int CY>
__global__ __launch_bounds__(256, 2) void gemm_bt(
    const ushort_t* __restrict__ A, const ushort_t* __restrict__ B0,
    const ushort_t* __restrict__ B1,
    const float* __restrict__ bias0, const float* __restrict__ bias1,
    OT* __restrict__ C0, OT* __restrict__ C1,
    int K, int lda, int ldb, int ldc, float scale,
    long long aOffZ, long long bOffZ, long long cOffZ)
{
    constexpr int P     = BK / 8;    // 16B positions per row
    constexpr int NCALL = BK / 16;   // staging calls per 128-row tile
    constexpr int RPC   = 2048 / BK; // rows per staging call (4 waves)

    __shared__ __align__(16) ushort_t As[128 * BK];
    __shared__ __align__(16) ushort_t Bs[NB][128 * BK];
    __shared__ float rs[128];        // EPI==4 only (512 B)

    const int tid  = threadIdx.x;
    const int wave = tid >> 6;
    const int lane = tid & 63;

    // ---- T1: bijective XCD-chunked remap (XCD = linear%8) ----
    const int GX  = gridDim.x, GY = gridDim.y, GZ = gridDim.z;
    const int bid = blockIdx.x + GX * (blockIdx.y + GY * blockIdx.z);
    const int xcd = bid & 7;
    const int jj  = bid >> 3;                    // 0..nwg/8-1 within XCD
    const int CZ  = (GX * GY * GZ) / (8 * CX * CY);
    const int NCX = GX / CX, NCY = GY / CY;
    const int cx  = xcd % NCX;
    const int ct  = xcd / NCX;
    const int cy  = ct % NCY, cz = ct / NCY;
    const int bx  = cx * CX + (jj % CX);
    const int by  = cy * CY + ((jj / CX) % CY);
    const int bz  = cz * CZ + jj / (CX * CY);

    A  += (size_t)bz * aOffZ;
    B0 += (size_t)bz * bOffZ;
    if (NB == 2) B1 += (size_t)bz * bOffZ;

    const int m0 = by * 128;
    const int n0 = bx * 128;
    const int wm = (wave >> 1) * 64;
    const int wn = (wave & 1) * 64;

    const unsigned ldsA  = (unsigned)(uintptr_t)&As[0];
    const unsigned ldsB0 = (unsigned)(uintptr_t)&Bs[0][0];
    const unsigned ldsB1 = (NB == 2) ? (unsigned)(uintptr_t)&Bs[NB - 1][0] : 0;

    // staging map: row-in-call, swizzled source chunk
    const int srow = wave * (RPC / 4) + lane / P;
    const int cd   = ((lane & (P - 1)) - srow) & (P - 1);
    const ushort_t* gA  = A  + (size_t)(m0 + srow) * lda + cd * 8;
    const ushort_t* gB0 = B0 + (size_t)(n0 + srow) * ldb + cd * 8;
    const ushort_t* gB1 = (NB == 2) ? B1 + (size_t)(n0 + srow) * ldb + cd * 8
                                    : nullptr;
    const unsigned lw = (wave << 10);

    // fragment map: lane -> row l&15; chunk (t*4 + l>>4) at swizzled pos
    const int frow = lane & 15;
    const int fg   = lane >> 4;

    f32x4 acc[NB][4][4] = {};
    float rsacc[4] = {0.f, 0.f, 0.f, 0.f};

    for (int k0 = 0; k0 < K; k0 += BK) {
        if (k0) __syncthreads();
#pragma unroll
        for (int c = 0; c < NCALL; ++c) {
            const size_t ro = (size_t)c * RPC;
            async_ld16(gA + ro * lda, ldsA + c * 4096 + lw);
            async_ld16(gB0 + ro * ldb, ldsB0 + c * 4096 + lw);
            if (NB == 2) async_ld16(gB1 + ro * ldb, ldsB1 + c * 4096 + lw);
        }
        gA += BK; gB0 += BK; if (NB == 2) gB1 += BK;
        __syncthreads();

#pragma unroll
        for (int t = 0; t < BK / 32; ++t) {
            const int pa = (((t << 2) + fg + frow) & (P - 1)) << 3;
            short8 af[4], bf[4];
#pragma unroll
            for (int i = 0; i < 4; ++i)
                af[i] = *(const short8*)&As[(wm + i * 16 + frow) * BK + pa];
            if (EPI == 4 && wn == 0) {   // rowsum of the streamed A tile
#pragma unroll
                for (int i = 0; i < 4; ++i)
#pragma unroll
                    for (int e = 0; e < 8; ++e)
                        rsacc[i] += bf2f((ushort_t)af[i][e]);
            }
#pragma unroll
            for (int j = 0; j < 4; ++j)
                bf[j] = *(const short8*)&Bs[0][(wn + j * 16 + frow) * BK + pa];
#pragma unroll
            for (int i = 0; i < 4; ++i)
#pragma unroll
                for (int j = 0; j < 4; ++j)
                    acc[0][i][j] = __builtin_amdgcn_mfma_f32_16x16x32_bf16(
                        af[i], bf[j], acc[0][i][j], 0, 0, 0);
            if (NB == 2) {
#pragma unroll
                for (int j = 0; j < 4; ++j)
                    bf[j] = *(const short8*)&Bs[NB - 1][(wn + j * 16 + frow) * BK + pa];
#pragma unroll
                for (int i = 0; i < 4; ++i)
#pragma unroll
                    for (int j = 0; j < 4; ++j)
                        acc[NB - 1][i][j] = __builtin_amdgcn_mfma_f32_16x16x32_bf16(
                            af[i], bf[j], acc[NB - 1][i][j], 0, 0, 0);
            }
        }
    }

    if (EPI == 4) {
        if (wn == 0) {
#pragma unroll
            for (int i = 0; i < 4; ++i) {
                float s = rsacc[i];
                s += __shfl_xor(s, 16, 64);
                s += __shfl_xor(s, 32, 64);
                rs[wm + i * 16 + frow] = s;   // 4 lanes, same value/addr
            }
        }
        __syncthreads();
    }

    // C/D layout: lane l reg r -> row (l>>4)*4+r, col l&15
    const int r0 = (lane >> 4) << 2;
    const int c0 = lane & 15;
#pragma unroll
    for (int o = 0; o < NB; ++o) {
        OT* C = (o == 0) ? C0 : C1;
        C += (size_t)bz * cOffZ;
        const float* bia = (o == 0) ? bias0 : bias1;
#pragma unroll
        for (int i = 0; i < 4; ++i) {
            float bm[4];
            if (EPI == 2) {
#pragma unroll
                for (int r = 0; r < 4; ++r)
                    bm[r] = bias0[m0 + wm + i * 16 + r0 + r];
            }
            if (EPI == 4) {
#pragma unroll
                for (int r = 0; r < 4; ++r)
                    bm[r] = 1.0f / rs[wm + i * 16 + r0 + r];
            }
#pragma unroll
            for (int j = 0; j < 4; ++j) {
                const int n = n0 + wn + j * 16 + c0;
                const float bn = (EPI == 1) ? bia[n] : 0.f;
#pragma unroll
                for (int r = 0; r < 4; ++r) {
                    const int m = m0 + wm + i * 16 + r0 + r;
                    float v = acc[o][i][j][r] * scale;
                    if (EPI == 1) v += bn;
                    if (EPI == 2) v += bm[r];
                    if (EPI == 3) v = __expf(v);
                    if (EPI == 4) v *= bm[r];
                    if constexpr (sizeof(OT) == 2)
                        C[(size_t)m * ldc + n] = f2bf(v);
                    else
                        C[(size_t)m * ldc + n] = v;
                }
            }
        }
    }
}

// one-shot fp32->bf16 cast of x, Wq, Wk, Wv (block-range dispatch)
__global__ __launch_bounds__(256) void cvt_all(
    const float* __restrict__ x,  const float* __restrict__ wq,
    const float* __restrict__ wk, const float* __restrict__ wv,
    ushort_t* __restrict__ xb,  ushort_t* __restrict__ wqb,
    ushort_t* __restrict__ wkb, ushort_t* __restrict__ wvb)
{
    const int b = blockIdx.x;
    const float* src; ushort_t* dst; size_t base;
    if (b < 4096)      { src = x;  dst = xb;  base = (size_t)b * 2048; }
    else if (b < 4608) { src = wq; dst = wqb; base = (size_t)(b - 4096) * 2048; }
    else if (b < 5120) { src = wk; dst = wkb; base = (size_t)(b - 4608) * 2048; }
    else               { src = wv; dst = wvb; base = (size_t)(b - 5120) * 2048; }
    const size_t i = base + threadIdx.x * 8;
    const f32x4 a = *(const f32x4*)(src + i);
    const f32x4 c = *(const f32x4*)(src + i + 4);
    short8 o;
    o[0] = (short)f2bf(a[0]); o[1] = (short)f2bf(a[1]);
    o[2] = (short)f2bf(a[2]); o[3] = (short)f2bf(a[3]);
    o[4] = (short)f2bf(c[0]); o[5] = (short)f2bf(c[1]);
    o[6] = (short)f2bf(c[2]); o[7] = (short)f2bf(c[3]);
    *(short8*)(dst + i) = o;
}

extern "C" void kernel_launch(void* const* d_in, const int* in_sizes, int n_in,
                              void* d_out, int out_size, void* d_ws, size_t ws_size,
                              hipStream_t stream)
{
    const float* x  = (const float*)d_in[0];
    const float* Wq = (const float*)d_in[1];
    const float* bq = (const float*)d_in[2];
    const float* Wk = (const float*)d_in[3];
    const float* bk = (const float*)d_in[4];
    const float* Wv = (const float*)d_in[5];
    const float* bv = (const float*)d_in[6];
    float* out = (float*)d_out;

    char* ws = (char*)d_ws;
    const size_t MB = 1ull << 20;
    ushort_t* Xb  = (ushort_t*)(ws);
    ushort_t* Wqb = (ushort_t*)(ws + 16 * MB);
    ushort_t* Wkb = (ushort_t*)(ws + 18 * MB);
    ushort_t* Wvb = (ushort_t*)(ws + 20 * MB);
    ushort_t* Qb  = (ushort_t*)(ws + 32 * MB);
    ushort_t* Kb  = (ushort_t*)(ws + 48 * MB);
    ushort_t* Vt  = (ushort_t*)(ws + 64 * MB);
    ushort_t* Sc  = (ushort_t*)(ws);             // reuses dead Xb/W region

    // 1) all casts in one launch
    cvt_all<<<dim3(5632), dim3(256), 0, stream>>>(
        x, Wq, Wk, Wv, Xb, Wqb, Wkb, Wvb);

    // 2) fused Q,K projection: stage X once, two weight tiles
    //    grid 8x64=512; chunk 4x x 16y per XCD (A 4MB + B 1MB in L2)
    gemm_bt<ushort_t, 1, 2, 64, 4, 16><<<dim3(8, 64, 1), dim3(256), 0, stream>>>(
        Xb, Wqb, Wkb, bq, bk, Qb, Kb, 1024, 1024, 1024, 1024, 1.0f, 0, 0, 0);

    // 3) Vt = Wv X^T + bv(row)  [1024,8192]
    //    grid 64x8=512; chunk 16x x 4y per XCD (A 1MB + B 4MB)
    gemm_bt<ushort_t, 2, 1, 64, 16, 4><<<dim3(64, 8, 1), dim3(256), 0, stream>>>(
        Wvb, Xb, nullptr, bv, nullptr, Vt, nullptr,
        1024, 1024, 1024, 8192, 1.0f, 0, 0, 0);

    // 4) Sc = exp(Q K^T / 32)  per batch (max-free softmax numerator)
    //    grid 16x16x4=1024; chunk 8x x 16y x 1z (Q 4MB + K 2MB per XCD)
    gemm_bt<ushort_t, 3, 1, 64, 8, 16><<<dim3(16, 16, 4), dim3(256), 0, stream>>>(
        Qb, Kb, nullptr, nullptr, nullptr, Sc, nullptr,
        1024, 1024, 1024, 2048, 0.03125f,
        2048ll * 1024, 2048ll * 1024, 2048ll * 2048);

    // 5) out = (Sc Vt^T) / rowsum(Sc row), rowsum fused in-kernel
    //    grid 8x16x4=512; chunk 8x x 8y x 1z (Sc 4MB + Vt 4MB per XCD)
    gemm_bt<float, 4, 1, 64, 8, 8><<<dim3(8, 16, 4), dim3(256), 0, stream>>>(
        Sc, Vt, nullptr, nullptr, nullptr, out, nullptr,
        2048, 2048, 8192, 1024, 1.0f,
        2048ll * 2048, 2048ll, 2048ll * 1024);
}

// Round 6
// 232.215 us; speedup vs baseline: 1.1175x; 1.0784x over previous
//
#include <hip/hip_runtime.h>
#include <cstdint>
#include <cstddef>

// FeatureAttention: x[4,2048,1024] fp32; Q=xWq^T+bq, K=xWk^T+bk, V=xWv^T+bv;
// out = softmax(QK^T/32) V.  bf16 MFMA pipeline.
//
// R10 = R9's 128x128 tile + chunked XCD remap (ideal FETCH, proven) with the
// staging schedule converted from stage->drain->compute (latency exposed every
// K-tile) to the guide's minimum 2-phase issue-early double-buffer:
//   prologue: stage(0); syncthreads
//   iter t:   stage(t+1) -> buf[(t+1)&1]    (issued FIRST)
//             compute(t) from buf[t&1]      (covers the load latency)
//             __syncthreads()               (vmcnt(0)+barrier, cheap now)
//   tail:     compute(NT-1)
// Safety: stage(t+2) overwrites buf[t&1] only after the barrier at end of t,
// which guarantees all waves finished reading buf[t&1].
// All four GEMMs are NB=1 (proj uses stacked Wq|Wk, N=2048, dual-bias EPI).
//
// Workspace (80 MB):
//   [0,16M)  Xb    [16,20) Wqkb (Wq|Wk stacked)  [20,22) Wvb
//   [32,64M) QKb   [8192][2048]: Q cols 0-1023, K cols 1024-2047
//   [64,80M) Vt    (V transposed [1024][8192])
//   [0,32M)  Sc    (exp(scores) bf16 [4][2048][2048], reuses dead region)

typedef unsigned short ushort_t;
typedef __attribute__((ext_vector_type(8))) short short8;
typedef __attribute__((ext_vector_type(4))) float f32x4;

#define AS1 __attribute__((address_space(1)))
#define AS3 __attribute__((address_space(3)))

__device__ __forceinline__ ushort_t f2bf(float f) {
    unsigned int u = __float_as_uint(f);
    u += 0x7FFFu + ((u >> 16) & 1u);
    return (ushort_t)(u >> 16);
}
__device__ __forceinline__ float bf2f(ushort_t b) {
    return __uint_as_float(((unsigned)b) << 16);
}

// async global->LDS, 16B/lane; lds dest = wave-uniform base + lane*16
__device__ __forceinline__ void async_ld16(const void* g, unsigned lds_off) {
    __builtin_amdgcn_global_load_lds((const AS1 void*)(uintptr_t)g,
                                     (AS3 void*)(uintptr_t)lds_off,
                                     16, 0, 0);
}

// ---------------------------------------------------------------------------
// Double-buffered BT-GEMM, 128x128 tile, BK=64, 256 threads (4 waves 2x2).
//   C[m*ldc+n] = epi( scale * sum_k A[m*lda+k] * B[n*ldb+k] )
// EPI: 1 +bias(n): n<1024 ? bias0[n] : bias1[n-1024]
//      2 +bias0[m] | 3 exp(v) | 4 v / rowsum(A-tile row m) (in-kernel rowsum)
// Bank swizzle: 16B chunk c of row r stored at position (c+r)&7, applied on
// the staging *source* chunk (global_load_lds lane->LDS map is fixed).
// CX,CY: XCD chunk dims (bijective remap; NCX*NCY*NCZ must equal 8).
// ---------------------------------------------------------------------------
template <typename OT, int EPI, int CX, int CY>
__global__ __launch_bounds__(256, 2) void gemm_db(
    const ushort_t* __restrict__ A, const ushort_t* __restrict__ B,
    const float* __restrict__ bias0, const float* __restrict__ bias1,
    OT* __restrict__ C, int K, int lda, int ldb, int ldc, float scale,
    long long aOffZ, long long bOffZ, long long cOffZ)
{
    constexpr int BK = 64;
    constexpr int P  = 8;           // 16B positions per row
    constexpr int NCALL = 4;        // staging calls per 128-row tile (32 rows ea)

    __shared__ __align__(16) ushort_t As[2][128 * BK];
    __shared__ __align__(16) ushort_t Bs[2][128 * BK];
    __shared__ float rs[128];       // EPI==4 only

    const int tid  = threadIdx.x;
    const int wave = tid >> 6;
    const int lane = tid & 63;

    // ---- bijective XCD-chunked remap (XCD = linear%8) ----
    const int GX  = gridDim.x, GY = gridDim.y, GZ = gridDim.z;
    const int bid = blockIdx.x + GX * (blockIdx.y + GY * blockIdx.z);
    const int xcd = bid & 7;
    const int jj  = bid >> 3;
    const int CZ  = (GX * GY * GZ) / (8 * CX * CY);
    const int NCX = GX / CX, NCY = GY / CY;
    const int cx  = xcd % NCX;
    const int ct  = xcd / NCX;
    const int cy  = ct % NCY, cz = ct / NCY;
    const int bx  = cx * CX + (jj % CX);
    const int by  = cy * CY + ((jj / CX) % CY);
    const int bz  = cz * CZ + jj / (CX * CY);

    A += (size_t)bz * aOffZ;
    B += (size_t)bz * bOffZ;

    const int m0 = by * 128;
    const int n0 = bx * 128;
    const int wm = (wave >> 1) * 64;
    const int wn = (wave & 1) * 64;

    const unsigned aB0 = (unsigned)(uintptr_t)&As[0][0];
    const unsigned aB1 = (unsigned)(uintptr_t)&As[1][0];
    const unsigned bB0 = (unsigned)(uintptr_t)&Bs[0][0];
    const unsigned bB1 = (unsigned)(uintptr_t)&Bs[1][0];

    // staging map: 32 rows/call, 8 rows/wave; swizzled source chunk
    const int srow = wave * 8 + (lane >> 3);
    const int cd   = ((lane & 7) - srow) & 7;
    const unsigned lw = (unsigned)(wave << 10);

    const ushort_t* gA = A + (size_t)(m0 + srow) * lda + cd * 8;
    const ushort_t* gB = B + (size_t)(n0 + srow) * ldb + cd * 8;

    // stage K-tile t into buf t&1 (8 calls: 4 A + 4 B)
    auto stage = [&](int t) {
        const int buf = t & 1;
        const ushort_t* pA = gA + (size_t)t * BK;
        const ushort_t* pB = gB + (size_t)t * BK;
        const unsigned la = (buf ? aB1 : aB0) + lw;
        const unsigned lb = (buf ? bB1 : bB0) + lw;
#pragma unroll
        for (int c = 0; c < NCALL; ++c) {
            async_ld16(pA + (size_t)(c * 32) * lda, la + c * 4096);
            async_ld16(pB + (size_t)(c * 32) * ldb, lb + c * 4096);
        }
    };

    // fragment map: lane -> row l&15; chunk (t2*4 + l>>4) at swizzled pos
    const int frow = lane & 15;
    const int fg   = lane >> 4;

    const int NT = K / BK;

    f32x4 acc[4][4] = {};
    float rsacc[4] = {0.f, 0.f, 0.f, 0.f};

    // one K-tile of compute from buffer `buf`
    auto compute = [&](int buf) {
        const ushort_t* Aw = &As[buf][0];
        const ushort_t* Bw = &Bs[buf][0];
#pragma unroll
        for (int t2 = 0; t2 < 2; ++t2) {
            const int pa = (((t2 << 2) + fg + frow) & 7) << 3;
            short8 af[4], bf[4];
#pragma unroll
            for (int i = 0; i < 4; ++i)
                af[i] = *(const short8*)&Aw[(wm + i * 16 + frow) * BK + pa];
            if (EPI == 4 && wn == 0) {   // rowsum of the streamed A tile
#pragma unroll
                for (int i = 0; i < 4; ++i)
#pragma unroll
                    for (int e = 0; e < 8; ++e)
                        rsacc[i] += bf2f((ushort_t)af[i][e]);
            }
#pragma unroll
            for (int j = 0; j < 4; ++j)
                bf[j] = *(const short8*)&Bw[(wn + j * 16 + frow) * BK + pa];
#pragma unroll
            for (int i = 0; i < 4; ++i)
#pragma unroll
                for (int j = 0; j < 4; ++j)
                    acc[i][j] = __builtin_amdgcn_mfma_f32_16x16x32_bf16(
                        af[i], bf[j], acc[i][j], 0, 0, 0);
        }
    };

    // prologue: stage tile 0, full drain once
    stage(0);
    __syncthreads();

    for (int t = 0; t < NT - 1; ++t) {
        stage(t + 1);        // issued early: latency hidden under compute(t)
        compute(t & 1);
        __syncthreads();     // vmcnt(0)+lgkmcnt(0)+barrier: tile t+1 landed,
                             // all waves done reading buf[t&1]
    }
    compute((NT - 1) & 1);   // tail: no prefetch, no barrier needed

    if (EPI == 4) {
        if (wn == 0) {
#pragma unroll
            for (int i = 0; i < 4; ++i) {
                float s = rsacc[i];
                s += __shfl_xor(s, 16, 64);
                s += __shfl_xor(s, 32, 64);
                rs[wm + i * 16 + frow] = s;   // 4 lanes, same value/addr
            }
        }
        __syncthreads();
    }

    // C/D layout: lane l reg r -> row (l>>4)*4+r, col l&15
    C += (size_t)bz * cOffZ;
    const int r0 = fg << 2;
    const int c0 = lane & 15;
#pragma unroll
    for (int i = 0; i < 4; ++i) {
        float bm[4];
        if (EPI == 2) {
#pragma unroll
            for (int r = 0; r < 4; ++r)
                bm[r] = bias0[m0 + wm + i * 16 + r0 + r];
        }
        if (EPI == 4) {
#pragma unroll
            for (int r = 0; r < 4; ++r)
                bm[r] = 1.0f / rs[wm + i * 16 + r0 + r];
        }
#pragma unroll
        for (int j = 0; j < 4; ++j) {
            const int n = n0 + wn + j * 16 + c0;
            float bn = 0.f;
            if (EPI == 1) bn = (n < 1024) ? bias0[n] : bias1[n - 1024];
#pragma unroll
            for (int r = 0; r < 4; ++r) {
                const int m = m0 + wm + i * 16 + r0 + r;
                float v = acc[i][j][r] * scale;
                if (EPI == 1) v += bn;
                if (EPI == 2) v += bm[r];
                if (EPI == 3) v = __expf(v);
                if (EPI == 4) v *= bm[r];
                if constexpr (sizeof(OT) == 2)
                    C[(size_t)m * ldc + n] = f2bf(v);
                else
                    C[(size_t)m * ldc + n] = v;
            }
        }
    }
}

// one-shot fp32->bf16 cast of x, Wq, Wk, Wv (block-range dispatch)
__global__ __launch_bounds__(256) void cvt_all(
    const float* __restrict__ x,  const float* __restrict__ wq,
    const float* __restrict__ wk, const float* __restrict__ wv,
    ushort_t* __restrict__ xb,  ushort_t* __restrict__ wqb,
    ushort_t* __restrict__ wkb, ushort_t* __restrict__ wvb)
{
    const int b = blockIdx.x;
    const float* src; ushort_t* dst; size_t base;
    if (b < 4096)      { src = x;  dst = xb;  base = (size_t)b * 2048; }
    else if (b < 4608) { src = wq; dst = wqb; base = (size_t)(b - 4096) * 2048; }
    else if (b < 5120) { src = wk; dst = wkb; base = (size_t)(b - 4608) * 2048; }
    else               { src = wv; dst = wvb; base = (size_t)(b - 5120) * 2048; }
    const size_t i = base + threadIdx.x * 8;
    const f32x4 a = *(const f32x4*)(src + i);
    const f32x4 c = *(const f32x4*)(src + i + 4);
    short8 o;
    o[0] = (short)f2bf(a[0]); o[1] = (short)f2bf(a[1]);
    o[2] = (short)f2bf(a[2]); o[3] = (short)f2bf(a[3]);
    o[4] = (short)f2bf(c[0]); o[5] = (short)f2bf(c[1]);
    o[6] = (short)f2bf(c[2]); o[7] = (short)f2bf(c[3]);
    *(short8*)(dst + i) = o;
}

extern "C" void kernel_launch(void* const* d_in, const int* in_sizes, int n_in,
                              void* d_out, int out_size, void* d_ws, size_t ws_size,
                              hipStream_t stream)
{
    const float* x  = (const float*)d_in[0];
    const float* Wq = (const float*)d_in[1];
    const float* bq = (const float*)d_in[2];
    const float* Wk = (const float*)d_in[3];
    const float* bk = (const float*)d_in[4];
    const float* Wv = (const float*)d_in[5];
    const float* bv = (const float*)d_in[6];
    float* out = (float*)d_out;

    char* ws = (char*)d_ws;
    const size_t MB = 1ull << 20;
    ushort_t* Xb   = (ushort_t*)(ws);
    ushort_t* Wqkb = (ushort_t*)(ws + 16 * MB);  // Wq rows 0-1023 | Wk rows 1024-2047
    ushort_t* Wvb  = (ushort_t*)(ws + 20 * MB);
    ushort_t* QKb  = (ushort_t*)(ws + 32 * MB);  // [8192][2048]: Q | K
    ushort_t* Vt   = (ushort_t*)(ws + 64 * MB);  // [1024][8192]
    ushort_t* Sc   = (ushort_t*)(ws);            // reuses dead Xb/W region

    // 1) all casts in one launch (wq -> ws+16M, wk -> ws+18M: stacked Wqkb)
    cvt_all<<<dim3(5632), dim3(256), 0, stream>>>(
        x, Wq, Wk, Wv, Xb, Wqkb, (ushort_t*)(ws + 18 * MB), Wvb);

    // 2) QK projection: A=Xb [8192x1024], B=Wqkb [2048x1024] -> QKb [8192x2048]
    //    grid 16x64=1024; chunk 8x x 16y (A 4MB + B 2MB per XCD)
    gemm_db<ushort_t, 1, 8, 16><<<dim3(16, 64, 1), dim3(256), 0, stream>>>(
        Xb, Wqkb, bq, bk, QKb, 1024, 1024, 1024, 2048, 1.0f, 0, 0, 0);

    // 3) Vt = Wv X^T + bv(row)  [1024,8192]
    //    grid 64x8=512; chunk 16x x 4y (A 1MB + B 4MB per XCD)
    gemm_db<ushort_t, 2, 16, 4><<<dim3(64, 8, 1), dim3(256), 0, stream>>>(
        Wvb, Xb, bv, nullptr, Vt, 1024, 1024, 1024, 8192, 1.0f, 0, 0, 0);

    // 4) Sc = exp(Q K^T / 32) per batch (max-free softmax numerator)
    //    grid 16x16x4=1024; chunk 8x x 16y x 1z (Q 4MB + K 2MB per XCD)
    gemm_db<ushort_t, 3, 8, 16><<<dim3(16, 16, 4), dim3(256), 0, stream>>>(
        QKb, QKb + 1024, nullptr, nullptr, Sc, 1024, 2048, 2048, 2048,
        0.03125f, 2048ll * 2048, 2048ll * 2048, 2048ll * 2048);

    // 5) out = (Sc Vt^T) / rowsum(Sc row), rowsum fused in-kernel
    //    grid 8x16x4=512; chunk 8x x 8y x 1z (Sc 4MB + Vt 4MB per XCD)
    gemm_db<float, 4, 8, 8><<<dim3(8, 16, 4), dim3(256), 0, stream>>>(
        Sc, Vt, nullptr, nullptr, out, 2048, 2048, 8192, 1024, 1.0f,
        2048ll * 2048, 2048ll, 2048ll * 1024);
}